// Round 6
// baseline (201.366 us; speedup 1.0000x reference)
//
#include <hip/hip_runtime.h>
#include <hip/hip_bf16.h>

#define SLEN 2048
#define HDIM 2048
#define NHEAD 32
#define KVHEAD 8
#define HEADD 64
#define NTOT 3104
#define NPAD 3200

typedef short bh8 __attribute__((ext_vector_type(8)));
typedef float f32x4 __attribute__((ext_vector_type(4)));

// 0.125 * log2(e): folded into Q so QK^T MFMA emits log2-domain scores
#define QSCALE 0.1803368801111204f

__device__ __forceinline__ unsigned short f2bf(float f) {
    union { float f; unsigned int u; } v; v.f = f;
    unsigned int u = v.u;
    return (unsigned short)((u + 0x7fffu + ((u >> 16) & 1u)) >> 16);
}

// HW packed f32->bf16 (RNE), 1 instruction instead of ~10 bit-ops
__device__ __forceinline__ unsigned int cvtpk_bf16(float lo, float hi) {
    unsigned int r;
    asm("v_cvt_pk_bf16_f32 %0, %1, %2" : "=v"(r) : "v"(lo), "v"(hi));
    return r;
}

__device__ __forceinline__ void gl_lds16(const unsigned short* g, unsigned short* l) {
    __builtin_amdgcn_global_load_lds(
        (const __attribute__((address_space(1))) unsigned int*)g,
        (__attribute__((address_space(3))) unsigned int*)l, 16, 0, 0);
}

// ---------------- cast hidden fp32 -> bf16 ----------------
__global__ void cast_x_k(const float* __restrict__ src, unsigned short* __restrict__ dst, int n) {
    int i = blockIdx.x * blockDim.x + threadIdx.x;
    int base = i * 4;
    if (base < n) {
        float4 f = *(const float4*)(src + base);
        ushort4 o;
        o.x = f2bf(f.x); o.y = f2bf(f.y); o.z = f2bf(f.z); o.w = f2bf(f.w);
        *(ushort4*)(dst + base) = o;
    }
}

// ---------------- pack [Wq|gates|Wk|Wv] transposed -> bf16 (NPAD x HDIM) ----------------
__global__ void pack_wt_k(const float* __restrict__ Wq, const float* __restrict__ Wk,
                          const float* __restrict__ Wv, unsigned short* __restrict__ Wt) {
    __shared__ float tile[32][33];
    int n0 = blockIdx.x * 32, k0 = blockIdx.y * 32;
    int t = threadIdx.x;
    for (int i = 0; i < 4; i++) {
        int idx = i * 256 + t;
        int kr = idx >> 5, nc = idx & 31;
        int n = n0 + nc, k = k0 + kr;
        float val = 0.f;
        if (n < 2048)       { int h = n >> 6, d = n & 63; val = Wq[(size_t)k * 2080 + (h >> 2) * 260 + (h & 3) * 64 + d]; }
        else if (n < 2080)  { int h = n - 2048;           val = Wq[(size_t)k * 2080 + (h >> 2) * 260 + 256 + (h & 3)]; }
        else if (n < 2592)  { val = Wk[(size_t)k * 512 + (n - 2080)]; }
        else if (n < 3104)  { val = Wv[(size_t)k * 512 + (n - 2592)]; }
        tile[kr][nc] = val;
    }
    __syncthreads();
    for (int i = 0; i < 4; i++) {
        int idx = i * 256 + t;
        int nr = idx >> 5, kc = idx & 31;
        Wt[(size_t)(n0 + nr) * HDIM + (k0 + kc)] = f2bf(tile[kc][nr]);
    }
}

// ---------------- transpose-cast Wo -> bf16 (2048 x 2048) ----------------
__global__ void pack_wot_k(const float* __restrict__ Wo, unsigned short* __restrict__ Wt) {
    __shared__ float tile[32][33];
    int n0 = blockIdx.x * 32, k0 = blockIdx.y * 32;
    int t = threadIdx.x;
    for (int i = 0; i < 4; i++) {
        int idx = i * 256 + t;
        int kr = idx >> 5, nc = idx & 31;
        tile[kr][nc] = Wo[(size_t)(k0 + kr) * 2048 + (n0 + nc)];
    }
    __syncthreads();
    for (int i = 0; i < 4; i++) {
        int idx = i * 256 + t;
        int nr = idx >> 5, kc = idx & 31;
        Wt[(size_t)(n0 + nr) * 2048 + (k0 + kc)] = f2bf(tile[kc][nr]);
    }
}

// ---------------- NT GEMM, 64x128 tile (unified QKV + out-proj) ----------------
// R6: 4-buffer pipeline with STATIC buffer indices (unroll-4 main loop + peeled tail)
// -- kills the ~110 VALU/step of rd/wr-rotate address recomputation (R5: VALUBusy 32%).
// Prefetch 3 tiles deep: steady-state vmcnt(6) (9 loads in flight, drain own stage's 3).
// setprio REMOVED (R5: -5% on lockstep GEMM, consistent with m190).
// Chunk XOR swizzle kept (R3: bank conflicts 3.28M -> 0).
__global__ __launch_bounds__(256) void gemm_nt64_k(const unsigned short* __restrict__ A,
                                                   const unsigned short* __restrict__ Bt,
                                                   float* __restrict__ C,
                                                   int ldc, int mtiles) {
    const int K = 2048;
    __shared__ unsigned short As[4][64 * 32];
    __shared__ unsigned short Bs[4][128 * 32];
    int d = blockIdx.x;
    int nwg = gridDim.x;
    int cpx = nwg >> 3;
    int swz = (d & 7) * cpx + (d >> 3);
    int m0 = (swz % mtiles) * 64, n0 = (swz / mtiles) * 128;
    int t = threadIdx.x;
    int w = t >> 6, l = t & 63;
    int wm = (w >> 1) * 32, wn = (w & 1) * 64;
    int lrow = l & 15, lc = l >> 4;
    int rsw = (lrow >> 1) & 3;
    int scol = ((l & 3) ^ ((l >> 3) & 3)) * 8;

    f32x4 acc[2][4];
    #pragma unroll
    for (int i = 0; i < 2; i++)
        #pragma unroll
        for (int j = 0; j < 4; j++)
            acc[i][j] = {0.f, 0.f, 0.f, 0.f};

    const unsigned short* ga = &A[(size_t)(m0 + w * 16 + (l >> 2)) * K + scol];
    const unsigned short* gb = &Bt[(size_t)(n0 + w * 32 + (l >> 2)) * K + scol];

#define STAGE_NT64(s, b) do { \
        gl_lds16(ga + (size_t)(s) * 32,                  &As[b][w * 512]); \
        gl_lds16(gb + (size_t)(s) * 32,                  &Bs[b][(w * 2 + 0) * 512]); \
        gl_lds16(gb + (size_t)(s) * 32 + 16 * (size_t)K, &Bs[b][(w * 2 + 1) * 512]); \
    } while (0)

#define GBODY(rb) do { \
        bh8 af[2], bb[4]; \
        _Pragma("unroll") \
        for (int i = 0; i < 2; i++) \
            af[i] = *(const bh8*)(&As[rb][(wm + i * 16 + lrow) * 32 + ((lc ^ rsw) * 8)]); \
        _Pragma("unroll") \
        for (int j = 0; j < 4; j++) \
            bb[j] = *(const bh8*)(&Bs[rb][(wn + j * 16 + lrow) * 32 + ((lc ^ rsw) * 8)]); \
        _Pragma("unroll") \
        for (int i = 0; i < 2; i++) \
            _Pragma("unroll") \
            for (int j = 0; j < 4; j++) \
                acc[i][j] = __builtin_amdgcn_mfma_f32_16x16x32_bf16(af[i], bb[j], acc[i][j], 0, 0, 0); \
    } while (0)

    // prologue: stage tiles 0,1,2 into bufs 0,1,2 (3 loads/wave each)
    STAGE_NT64(0, 0);
    STAGE_NT64(1, 1);
    STAGE_NT64(2, 2);
    // main: iters s=0..59 (s&3 static via unroll-4); iter s drains stage s (vmcnt 6),
    // stages s+3 into buf (s+3)&3 (last read iter s-1, ordered by this barrier).
    for (int sb = 0; sb < 60; sb += 4) {
        asm volatile("s_waitcnt vmcnt(6)\n\ts_barrier" ::: "memory");
        STAGE_NT64(sb + 3, 3);
        GBODY(0);
        asm volatile("s_waitcnt vmcnt(6)\n\ts_barrier" ::: "memory");
        STAGE_NT64(sb + 4, 0);
        GBODY(1);
        asm volatile("s_waitcnt vmcnt(6)\n\ts_barrier" ::: "memory");
        STAGE_NT64(sb + 5, 1);
        GBODY(2);
        asm volatile("s_waitcnt vmcnt(6)\n\ts_barrier" ::: "memory");
        STAGE_NT64(sb + 6, 2);
        GBODY(3);
    }
    // peeled tail: s = 60 (stage 63), 61, 62, 63 (waits 6,6,3,0)
    asm volatile("s_waitcnt vmcnt(6)\n\ts_barrier" ::: "memory");
    STAGE_NT64(63, 3);
    GBODY(0);
    asm volatile("s_waitcnt vmcnt(6)\n\ts_barrier" ::: "memory");
    GBODY(1);
    asm volatile("s_waitcnt vmcnt(3)\n\ts_barrier" ::: "memory");
    GBODY(2);
    asm volatile("s_waitcnt vmcnt(0)\n\ts_barrier" ::: "memory");
    GBODY(3);
#undef STAGE_NT64
#undef GBODY
    int col = l & 15, rbase = (l >> 4) * 4;
    for (int i = 0; i < 2; i++)
        for (int j = 0; j < 4; j++)
            #pragma unroll
            for (int r = 0; r < 4; r++)
                C[(size_t)(m0 + wm + i * 16 + rbase + r) * ldc + (n0 + wn + j * 16 + col)] = acc[i][j][r];
}

// ---------------- RMSNorm + RoPE for Q,K (Q pre-scaled by 0.125*log2e) ----------------
__global__ void norm_rope_k(const float* __restrict__ QKVG, unsigned short* __restrict__ Qr,
                            unsigned short* __restrict__ Kr,
                            const float* __restrict__ g_q, const float* __restrict__ g_k) {
    int wid = blockIdx.x * (blockDim.x >> 6) + (threadIdx.x >> 6);
    int lane = threadIdx.x & 63;
    int type, s, hh;
    if (wid < SLEN * NHEAD) { type = 0; s = wid >> 5; hh = wid & 31; }
    else                    { int r = wid - SLEN * NHEAD; type = 1; s = r >> 3; hh = r & 7; }
    int col = (type == 0) ? hh * 64 + lane : 2080 + hh * 64 + lane;
    float x = QKVG[(size_t)s * NPAD + col];
    float sq = x * x;
    #pragma unroll
    for (int off = 32; off; off >>= 1) sq += __shfl_xor(sq, off);
    float inv = rsqrtf(sq * (1.f / 64.f) + 1e-6f);
    float g = (type == 0 ? g_q : g_k)[lane];
    float xn = x * inv * g;
    float xp = __shfl_xor(xn, 32);
    float xr = (lane < 32) ? -xp : xp;
    int i = lane & 31;
    float invf = __expf(-(float)i * (0.03125f * 13.815510557964274f));
    float ang = (float)s * invf;
    float c = cosf(ang), sn = sinf(ang);
    float r = xn * c + xr * sn;
    if (type == 0) Qr[((size_t)hh * SLEN + s) * 64 + lane] = f2bf(r * QSCALE);
    else           Kr[((size_t)hh * SLEN + s) * 64 + lane] = f2bf(r);
}

// ---------------- V transpose + key-permute: QKVG[s][2592+hh*64+d] -> Vt[hh][d][perm(s)] ----
// Within each 64-key block, key k = 32*hb + 16*f + 4*g + j stored at position (hb*4+g)*8 + f*4 + j,
// so the PV B-fragment (keys {4g..4g+3, 16+4g..} for half hh) is one contiguous 16B chunk.
__global__ void vt_k(const float* __restrict__ QKVG, unsigned short* __restrict__ Vt) {
    __shared__ float tile[64][65];
    int s0 = blockIdx.x * 64, hh = blockIdx.y;
    int t = threadIdx.x;
    #pragma unroll
    for (int i = 0; i < 4; i++) {
        int idx = i * 256 + t;
        int sr = idx >> 4, c4 = (idx & 15) * 4;
        float4 f = *(const float4*)(&QKVG[(size_t)(s0 + sr) * NPAD + 2592 + hh * 64 + c4]);
        tile[sr][c4] = f.x; tile[sr][c4 + 1] = f.y; tile[sr][c4 + 2] = f.z; tile[sr][c4 + 3] = f.w;
    }
    __syncthreads();
    #pragma unroll
    for (int i = 0; i < 4; i++) {
        int idx = i * 256 + t;
        int dr = idx >> 4, c4 = (idx & 15) * 4;
        int hb = c4 >> 5, f = (c4 >> 4) & 1, g = (c4 >> 2) & 3;
        int p = (hb * 4 + g) * 8 + f * 4;
        ushort4 o;
        o.x = f2bf(tile[c4][dr]); o.y = f2bf(tile[c4 + 1][dr]);
        o.z = f2bf(tile[c4 + 2][dr]); o.w = f2bf(tile[c4 + 3][dr]);
        *(ushort4*)(&Vt[((size_t)hh * 64 + dr) * SLEN + s0 + p]) = o;
    }
}

// ---------------- sigmoid(gate) ----------------
__global__ void gate_sig_k(const float* __restrict__ QKVG, float* __restrict__ gate) {
    int i = blockIdx.x * 256 + threadIdx.x;
    int s = i >> 5, h = i & 31;
    float x = QKVG[(size_t)s * NPAD + 2048 + h];
    gate[i] = 1.f / (1.f + __expf(-x));
}

// ---------------- causal GQA flash attention + gate ----------------
// R4: one q-tile per block (grid 1024, big-first order for LPT packing) -> 3 blocks/CU
// (LDS-capped at 48KB), 12 waves/CU. R2's 3-buffer counted-vmcnt pipeline.
// setprio kept here (attn blocks run at independent phases; m191 +4-7%).
__global__ __launch_bounds__(256) void attn_k(const unsigned short* __restrict__ Qr,
                                              const unsigned short* __restrict__ Kr,
                                              const unsigned short* __restrict__ Vt,
                                              const float* __restrict__ gate,
                                              unsigned short* __restrict__ attn) {
    __shared__ unsigned short Kls[3][64 * 64];
    __shared__ unsigned short Vls[3][64 * 64];
    int d = blockIdx.x;
    int kvh = d & 7;
    int h = kvh * 4 + ((d >> 3) & 3);
    int qt = 31 - (d >> 5);          // big-first: span-32 blocks dispatch first
    int t = threadIdx.x, w = t >> 6, l = t & 63;
    int ql = l & 15, g = l >> 4;
    const float NEGINF = -__builtin_inff();

    const unsigned short* Kh = Kr + (size_t)kvh * SLEN * 64;
    const unsigned short* Vh = Vt + (size_t)kvh * 64 * SLEN;
    const unsigned short* Qh = Qr + (size_t)h * SLEN * 64;
    int lk = g * 8;
    // staging lane geometry: 8 rows x 8 chunks of 16B per gl_lds16
    int r8 = l >> 3, c8 = l & 7;
    int cs = 8 * (c8 ^ r8);          // pre-swizzled source col (shorts)
    int R0 = w * 16, R1 = w * 16 + 8;
    int rdswz = (ql & 7) << 4;       // read-side XOR swizzle (bytes)

    int q0 = qt * 64;
    int qrow = q0 + w * 16 + ql;

    bh8 qa0 = *(const bh8*)(Qh + (size_t)qrow * 64 + lk);
    bh8 qa1 = *(const bh8*)(Qh + (size_t)qrow * 64 + 32 + lk);

    f32x4 o[4];
    #pragma unroll
    for (int i = 0; i < 4; i++) o[i] = {0.f, 0.f, 0.f, 0.f};
    float m2 = NEGINF, lsum = 0.f;

    int ntiles = qt + 1;
    // prologue: stage tile 0 -> buf0, tile 1 -> buf1 (4 loads/wave each)
    {
        gl_lds16(&Kh[(size_t)(0 + R0 + r8) * 64 + cs], &Kls[0][R0 * 64]);
        gl_lds16(&Kh[(size_t)(0 + R1 + r8) * 64 + cs], &Kls[0][R1 * 64]);
        gl_lds16(&Vh[(size_t)(R0 + r8) * SLEN + 0 + cs], &Vls[0][R0 * 64]);
        gl_lds16(&Vh[(size_t)(R1 + r8) * SLEN + 0 + cs], &Vls[0][R1 * 64]);
    }
    if (ntiles > 1) {
        gl_lds16(&Kh[(size_t)(64 + R0 + r8) * 64 + cs], &Kls[1][R0 * 64]);
        gl_lds16(&Kh[(size_t)(64 + R1 + r8) * 64 + cs], &Kls[1][R1 * 64]);
        gl_lds16(&Vh[(size_t)(R0 + r8) * SLEN + 64 + cs], &Vls[1][R0 * 64]);
        gl_lds16(&Vh[(size_t)(R1 + r8) * SLEN + 64 + cs], &Vls[1][R1 * 64]);
    }
    int rd = 0, wr = 2;

    for (int ti = 0; ti < ntiles; ti++) {
        // wait my tile-ti loads (keep tile-ti+1 in flight), then sync all waves.
        if (ti + 1 < ntiles) asm volatile("s_waitcnt vmcnt(4)\n\ts_barrier" ::: "memory");
        else                 asm volatile("s_waitcnt vmcnt(0)\n\ts_barrier" ::: "memory");
        // stage tile ti+2 into buf[wr] (last read at iter ti-1; barrier ordered it)
        if (ti + 2 < ntiles) {
            int kv1 = (ti + 2) * 64;
            gl_lds16(&Kh[(size_t)(kv1 + R0 + r8) * 64 + cs], &Kls[wr][R0 * 64]);
            gl_lds16(&Kh[(size_t)(kv1 + R1 + r8) * 64 + cs], &Kls[wr][R1 * 64]);
            gl_lds16(&Vh[(size_t)(R0 + r8) * SLEN + kv1 + cs], &Vls[wr][R0 * 64]);
            gl_lds16(&Vh[(size_t)(R1 + r8) * SLEN + kv1 + cs], &Vls[wr][R1 * 64]);
        }
        const unsigned short* Kb = &Kls[rd][0];
        const unsigned short* Vb = &Vls[rd][0];
        int kv0 = ti * 64;
        // ---- QK^T (swapped): sct[nt][j] = S^T[key=kv0+nt*16+4g+j][q=qrow] (log2 units)
        f32x4 sct[4];
        __builtin_amdgcn_s_setprio(1);
        #pragma unroll
        for (int nt = 0; nt < 4; nt++) {
            int rb = (nt * 16 + ql) * 128;
            bh8 kb0 = *(const bh8*)(&Kb[(rb + ((g * 16) ^ rdswz)) >> 1]);
            bh8 kb1 = *(const bh8*)(&Kb[(rb + ((64 + g * 16) ^ rdswz)) >> 1]);
            f32x4 a = {0.f, 0.f, 0.f, 0.f};
            a = __builtin_amdgcn_mfma_f32_16x16x32_bf16(kb0, qa0, a, 0, 0, 0);
            a = __builtin_amdgcn_mfma_f32_16x16x32_bf16(kb1, qa1, a, 0, 0, 0);
            sct[nt] = a;
        }
        __builtin_amdgcn_s_setprio(0);
        // ---- causal mask (diag tile only)
        if (ti == qt) {
            #pragma unroll
            for (int nt = 0; nt < 4; nt++)
                #pragma unroll
                for (int j = 0; j < 4; j++) {
                    int key = kv0 + nt * 16 + 4 * g + j;
                    if (key > qrow) sct[nt][j] = NEGINF;
                }
        }
        // ---- online softmax (log2 domain), per-q reduce = regs + 2 shfl
        float mt0 = fmaxf(fmaxf(sct[0][0], sct[0][1]), fmaxf(sct[0][2], sct[0][3]));
        float mt1 = fmaxf(fmaxf(sct[1][0], sct[1][1]), fmaxf(sct[1][2], sct[1][3]));
        float mt2 = fmaxf(fmaxf(sct[2][0], sct[2][1]), fmaxf(sct[2][2], sct[2][3]));
        float mt3 = fmaxf(fmaxf(sct[3][0], sct[3][1]), fmaxf(sct[3][2], sct[3][3]));
        float mt = fmaxf(fmaxf(mt0, mt1), fmaxf(mt2, mt3));
        mt = fmaxf(mt, __shfl_xor(mt, 16));
        mt = fmaxf(mt, __shfl_xor(mt, 32));
        // defer-max: only rescale when tile max beats running max by >8 (log2 units)
        if (!__all(mt - m2 <= 8.f)) {
            float mnew = fmaxf(m2, mt);
            float resc = __builtin_amdgcn_exp2f(m2 - mnew);
            m2 = mnew;
            lsum *= resc;
            float rf[4];
            #pragma unroll
            for (int j = 0; j < 4; j++) rf[j] = __shfl(resc, 4 * g + j);
            #pragma unroll
            for (int nt = 0; nt < 4; nt++) {
                f32x4 oo = o[nt];
                #pragma unroll
                for (int j = 0; j < 4; j++) oo[j] *= rf[j];
                o[nt] = oo;
            }
        }
        float ps = 0.f;
        #pragma unroll
        for (int nt = 0; nt < 4; nt++)
            #pragma unroll
            for (int j = 0; j < 4; j++) {
                float p = __builtin_amdgcn_exp2f(sct[nt][j] - m2);
                sct[nt][j] = p;
                ps += p;
            }
        ps += __shfl_xor(ps, 16);
        ps += __shfl_xor(ps, 32);
        lsum += ps;
        // ---- P -> bf16 A-fragments, lane-local (key-permutation pi), HW cvt_pk
        union { unsigned int u[4]; bh8 v; } pa0, pa1;
        pa0.u[0] = cvtpk_bf16(sct[0][0], sct[0][1]);
        pa0.u[1] = cvtpk_bf16(sct[0][2], sct[0][3]);
        pa0.u[2] = cvtpk_bf16(sct[1][0], sct[1][1]);
        pa0.u[3] = cvtpk_bf16(sct[1][2], sct[1][3]);
        pa1.u[0] = cvtpk_bf16(sct[2][0], sct[2][1]);
        pa1.u[1] = cvtpk_bf16(sct[2][2], sct[2][3]);
        pa1.u[2] = cvtpk_bf16(sct[3][0], sct[3][1]);
        pa1.u[3] = cvtpk_bf16(sct[3][2], sct[3][3]);
        // ---- PV: B-fragments are single b128 reads (Vt key order pre-permuted)
        __builtin_amdgcn_s_setprio(1);
        #pragma unroll
        for (int nt = 0; nt < 4; nt++) {
            int rb = (nt * 16 + ql) * 128;
            bh8 vb0 = *(const bh8*)(&Vb[(rb + ((g * 16) ^ rdswz)) >> 1]);
            bh8 vb1 = *(const bh8*)(&Vb[(rb + ((64 + g * 16) ^ rdswz)) >> 1]);
            o[nt] = __builtin_amdgcn_mfma_f32_16x16x32_bf16(pa0.v, vb0, o[nt], 0, 0, 0);
            o[nt] = __builtin_amdgcn_mfma_f32_16x16x32_bf16(pa1.v, vb1, o[nt], 0, 0, 0);
        }
        __builtin_amdgcn_s_setprio(0);
        rd = (rd == 2) ? 0 : rd + 1;
        wr = (wr == 2) ? 0 : wr + 1;
    }

    // ---- epilogue: normalize, gate, store (o row q = 4g+j, col d = nt*16+ql)
    float gf[4];
    #pragma unroll
    for (int j = 0; j < 4; j++) {
        float ls = __shfl(lsum, 4 * g + j);
        int row = q0 + w * 16 + 4 * g + j;
        gf[j] = gate[row * 32 + h] / ls;
    }
    #pragma unroll
    for (int j = 0; j < 4; j++) {
        int row = q0 + w * 16 + 4 * g + j;
        #pragma unroll
        for (int nt = 0; nt < 4; nt++)
            attn[(size_t)row * 2048 + h * 64 + nt * 16 + ql] = f2bf(o[nt][j] * gf[j]);
    }
}

extern "C" void kernel_launch(void* const* d_in, const int* in_sizes, int n_in,
                              void* d_out, int out_size, void* d_ws, size_t ws_size,
                              hipStream_t stream) {
    const float* hidden = (const float*)d_in[0];
    const float* Wq = (const float*)d_in[1];
    const float* Wk = (const float*)d_in[2];
    const float* Wv = (const float*)d_in[3];
    const float* Wo = (const float*)d_in[4];
    const float* gq = (const float*)d_in[5];
    const float* gk = (const float*)d_in[6];
    float* out = (float*)d_out;
    char* ws = (char*)d_ws;

    unsigned short* X    = (unsigned short*)(ws + 0);         //  8388608 B
    unsigned short* Wt   = (unsigned short*)(ws + 8388608);   // 13107200 B
    float*          QKVG = (float*)(ws + 21495808);           // 26214400 B
    unsigned short* Qr   = (unsigned short*)(ws + 47710208);  //  8388608 B
    unsigned short* Kr   = (unsigned short*)(ws + 56098816);  //  2097152 B
    unsigned short* Vt   = (unsigned short*)(ws + 58195968);  //  2097152 B
    float*          gate = (float*)(ws + 60293120);           //   262144 B
    unsigned short* attn = (unsigned short*)(ws + 60555264);  //  8388608 B
    unsigned short* Wot  = (unsigned short*)(ws + 68943872);  //  8388608 B

    cast_x_k<<<dim3(4096), dim3(256), 0, stream>>>(hidden, X, SLEN * HDIM);
    pack_wt_k<<<dim3(100, 64), dim3(256), 0, stream>>>(Wq, Wk, Wv, Wt);
    pack_wot_k<<<dim3(64, 64), dim3(256), 0, stream>>>(Wo, Wot);
    gemm_nt64_k<<<dim3(800), dim3(256), 0, stream>>>(X, Wt, QKVG, NPAD, 32);
    norm_rope_k<<<dim3(20480), dim3(256), 0, stream>>>(QKVG, Qr, Kr, gq, gk);
    vt_k<<<dim3(32, 8), dim3(256), 0, stream>>>(QKVG, Vt);
    gate_sig_k<<<dim3(256), dim3(256), 0, stream>>>(QKVG, gate);
    attn_k<<<dim3(1024), dim3(256), 0, stream>>>(Qr, Kr, Vt, gate, attn);
    gemm_nt64_k<<<dim3(512), dim3(256), 0, stream>>>(attn, Wot, out, 2048, 32);
}

// Round 7
// 168.460 us; speedup vs baseline: 1.1953x; 1.1953x over previous
//
#include <hip/hip_runtime.h>
#include <hip/hip_bf16.h>

#define SLEN 2048
#define HDIM 2048
#define NHEAD 32
#define KVHEAD 8
#define HEADD 64
#define NTOT 3104
#define NPAD 3200

typedef short bh8 __attribute__((ext_vector_type(8)));
typedef float f32x4 __attribute__((ext_vector_type(4)));

// 0.125 * log2(e): folded into Q so QK^T MFMA emits log2-domain scores
#define QSCALE 0.1803368801111204f

__device__ __forceinline__ unsigned short f2bf(float f) {
    union { float f; unsigned int u; } v; v.f = f;
    unsigned int u = v.u;
    return (unsigned short)((u + 0x7fffu + ((u >> 16) & 1u)) >> 16);
}

// HW packed f32->bf16 (RNE), 1 instruction instead of ~10 bit-ops
__device__ __forceinline__ unsigned int cvtpk_bf16(float lo, float hi) {
    unsigned int r;
    asm("v_cvt_pk_bf16_f32 %0, %1, %2" : "=v"(r) : "v"(lo), "v"(hi));
    return r;
}

__device__ __forceinline__ void gl_lds16(const unsigned short* g, unsigned short* l) {
    __builtin_amdgcn_global_load_lds(
        (const __attribute__((address_space(1))) unsigned int*)g,
        (__attribute__((address_space(3))) unsigned int*)l, 16, 0, 0);
}

// ---------------- cast hidden fp32 -> bf16 ----------------
__global__ void cast_x_k(const float* __restrict__ src, unsigned short* __restrict__ dst, int n) {
    int i = blockIdx.x * blockDim.x + threadIdx.x;
    int base = i * 4;
    if (base < n) {
        float4 f = *(const float4*)(src + base);
        ushort4 o;
        o.x = f2bf(f.x); o.y = f2bf(f.y); o.z = f2bf(f.z); o.w = f2bf(f.w);
        *(ushort4*)(dst + base) = o;
    }
}

// ---------------- pack [Wq|gates|Wk|Wv] transposed -> bf16 (NPAD x HDIM) ----------------
__global__ void pack_wt_k(const float* __restrict__ Wq, const float* __restrict__ Wk,
                          const float* __restrict__ Wv, unsigned short* __restrict__ Wt) {
    __shared__ float tile[32][33];
    int n0 = blockIdx.x * 32, k0 = blockIdx.y * 32;
    int t = threadIdx.x;
    for (int i = 0; i < 4; i++) {
        int idx = i * 256 + t;
        int kr = idx >> 5, nc = idx & 31;
        int n = n0 + nc, k = k0 + kr;
        float val = 0.f;
        if (n < 2048)       { int h = n >> 6, d = n & 63; val = Wq[(size_t)k * 2080 + (h >> 2) * 260 + (h & 3) * 64 + d]; }
        else if (n < 2080)  { int h = n - 2048;           val = Wq[(size_t)k * 2080 + (h >> 2) * 260 + 256 + (h & 3)]; }
        else if (n < 2592)  { val = Wk[(size_t)k * 512 + (n - 2080)]; }
        else if (n < 3104)  { val = Wv[(size_t)k * 512 + (n - 2592)]; }
        tile[kr][nc] = val;
    }
    __syncthreads();
    for (int i = 0; i < 4; i++) {
        int idx = i * 256 + t;
        int nr = idx >> 5, kc = idx & 31;
        Wt[(size_t)(n0 + nr) * HDIM + (k0 + kc)] = f2bf(tile[kc][nr]);
    }
}

// ---------------- transpose-cast Wo -> bf16 (2048 x 2048) ----------------
__global__ void pack_wot_k(const float* __restrict__ Wo, unsigned short* __restrict__ Wt) {
    __shared__ float tile[32][33];
    int n0 = blockIdx.x * 32, k0 = blockIdx.y * 32;
    int t = threadIdx.x;
    for (int i = 0; i < 4; i++) {
        int idx = i * 256 + t;
        int kr = idx >> 5, nc = idx & 31;
        tile[kr][nc] = Wo[(size_t)(k0 + kr) * 2048 + (n0 + nc)];
    }
    __syncthreads();
    for (int i = 0; i < 4; i++) {
        int idx = i * 256 + t;
        int nr = idx >> 5, kc = idx & 31;
        Wt[(size_t)(n0 + nr) * 2048 + (k0 + kc)] = f2bf(tile[kc][nr]);
    }
}

// ---------------- NT GEMM, 64x128 tile (unified QKV + out-proj) ----------------
// R7 = R5's 3-buffer/36KB geometry (4 blocks/CU, occupancy 28%) + R6's static buffer
// indices (unroll-3 main loop, VALUBusy 12%). R6's 4th buffer crossed the LDS occupancy
// cliff (48KB -> 3 blocks/CU) and cost 28% despite lower VALU -- reverted.
// 2-deep prefetch, per-wave 3 loads/step -> steady-state s_waitcnt vmcnt(3).
__global__ __launch_bounds__(256) void gemm_nt64_k(const unsigned short* __restrict__ A,
                                                   const unsigned short* __restrict__ Bt,
                                                   float* __restrict__ C,
                                                   int ldc, int mtiles) {
    const int K = 2048;
    __shared__ unsigned short As[3][64 * 32];
    __shared__ unsigned short Bs[3][128 * 32];
    int d = blockIdx.x;
    int nwg = gridDim.x;
    int cpx = nwg >> 3;
    int swz = (d & 7) * cpx + (d >> 3);
    int m0 = (swz % mtiles) * 64, n0 = (swz / mtiles) * 128;
    int t = threadIdx.x;
    int w = t >> 6, l = t & 63;
    int wm = (w >> 1) * 32, wn = (w & 1) * 64;
    int lrow = l & 15, lc = l >> 4;
    int rsw = (lrow >> 1) & 3;
    int scol = ((l & 3) ^ ((l >> 3) & 3)) * 8;

    f32x4 acc[2][4];
    #pragma unroll
    for (int i = 0; i < 2; i++)
        #pragma unroll
        for (int j = 0; j < 4; j++)
            acc[i][j] = {0.f, 0.f, 0.f, 0.f};

    const unsigned short* ga = &A[(size_t)(m0 + w * 16 + (l >> 2)) * K + scol];
    const unsigned short* gb = &Bt[(size_t)(n0 + w * 32 + (l >> 2)) * K + scol];

#define STAGE_NT64(s, b) do { \
        gl_lds16(ga + (size_t)(s) * 32,                  &As[b][w * 512]); \
        gl_lds16(gb + (size_t)(s) * 32,                  &Bs[b][(w * 2 + 0) * 512]); \
        gl_lds16(gb + (size_t)(s) * 32 + 16 * (size_t)K, &Bs[b][(w * 2 + 1) * 512]); \
    } while (0)

#define GBODY(rb) do { \
        bh8 af[2], bb[4]; \
        _Pragma("unroll") \
        for (int i = 0; i < 2; i++) \
            af[i] = *(const bh8*)(&As[rb][(wm + i * 16 + lrow) * 32 + ((lc ^ rsw) * 8)]); \
        _Pragma("unroll") \
        for (int j = 0; j < 4; j++) \
            bb[j] = *(const bh8*)(&Bs[rb][(wn + j * 16 + lrow) * 32 + ((lc ^ rsw) * 8)]); \
        _Pragma("unroll") \
        for (int i = 0; i < 2; i++) \
            _Pragma("unroll") \
            for (int j = 0; j < 4; j++) \
                acc[i][j] = __builtin_amdgcn_mfma_f32_16x16x32_bf16(af[i], bb[j], acc[i][j], 0, 0, 0); \
    } while (0)

#define WB3 asm volatile("s_waitcnt vmcnt(3)\n\ts_barrier" ::: "memory")

    // prologue: stage tiles 0,1 into bufs 0,1 (3 loads/wave each; 6 outstanding)
    STAGE_NT64(0, 0);
    STAGE_NT64(1, 1);
    // main: s=0..59, unroll-3 so s%3 is static. Iter s: drain stage s (vmcnt(3)),
    // barrier, stage s+2 into buf (s+2)%3 (last read iter s-1, barrier-ordered).
    for (int sb = 0; sb < 60; sb += 3) {
        WB3;
        STAGE_NT64(sb + 2, 2);
        GBODY(0);
        WB3;
        STAGE_NT64(sb + 3, 0);
        GBODY(1);
        WB3;
        STAGE_NT64(sb + 4, 1);
        GBODY(2);
    }
    // peeled tail: s = 60 (stage 62), 61 (stage 63), 62, 63
    WB3;
    STAGE_NT64(62, 2);
    GBODY(0);
    WB3;
    STAGE_NT64(63, 0);
    GBODY(1);
    WB3;
    GBODY(2);
    asm volatile("s_waitcnt vmcnt(0)\n\ts_barrier" ::: "memory");
    GBODY(0);
#undef WB3
#undef STAGE_NT64
#undef GBODY
    int col = l & 15, rbase = (l >> 4) * 4;
    for (int i = 0; i < 2; i++)
        for (int j = 0; j < 4; j++)
            #pragma unroll
            for (int r = 0; r < 4; r++)
                C[(size_t)(m0 + wm + i * 16 + rbase + r) * ldc + (n0 + wn + j * 16 + col)] = acc[i][j][r];
}

// ---------------- RMSNorm + RoPE for Q,K (Q pre-scaled by 0.125*log2e) ----------------
__global__ void norm_rope_k(const float* __restrict__ QKVG, unsigned short* __restrict__ Qr,
                            unsigned short* __restrict__ Kr,
                            const float* __restrict__ g_q, const float* __restrict__ g_k) {
    int wid = blockIdx.x * (blockDim.x >> 6) + (threadIdx.x >> 6);
    int lane = threadIdx.x & 63;
    int type, s, hh;
    if (wid < SLEN * NHEAD) { type = 0; s = wid >> 5; hh = wid & 31; }
    else                    { int r = wid - SLEN * NHEAD; type = 1; s = r >> 3; hh = r & 7; }
    int col = (type == 0) ? hh * 64 + lane : 2080 + hh * 64 + lane;
    float x = QKVG[(size_t)s * NPAD + col];
    float sq = x * x;
    #pragma unroll
    for (int off = 32; off; off >>= 1) sq += __shfl_xor(sq, off);
    float inv = rsqrtf(sq * (1.f / 64.f) + 1e-6f);
    float g = (type == 0 ? g_q : g_k)[lane];
    float xn = x * inv * g;
    float xp = __shfl_xor(xn, 32);
    float xr = (lane < 32) ? -xp : xp;
    int i = lane & 31;
    float invf = __expf(-(float)i * (0.03125f * 13.815510557964274f));
    float ang = (float)s * invf;
    float c = cosf(ang), sn = sinf(ang);
    float r = xn * c + xr * sn;
    if (type == 0) Qr[((size_t)hh * SLEN + s) * 64 + lane] = f2bf(r * QSCALE);
    else           Kr[((size_t)hh * SLEN + s) * 64 + lane] = f2bf(r);
}

// ---------------- V transpose + key-permute: QKVG[s][2592+hh*64+d] -> Vt[hh][d][perm(s)] ----
// Within each 64-key block, key k = 32*hb + 16*f + 4*g + j stored at position (hb*4+g)*8 + f*4 + j,
// so the PV B-fragment (keys {4g..4g+3, 16+4g..} for half hh) is one contiguous 16B chunk.
__global__ void vt_k(const float* __restrict__ QKVG, unsigned short* __restrict__ Vt) {
    __shared__ float tile[64][65];
    int s0 = blockIdx.x * 64, hh = blockIdx.y;
    int t = threadIdx.x;
    #pragma unroll
    for (int i = 0; i < 4; i++) {
        int idx = i * 256 + t;
        int sr = idx >> 4, c4 = (idx & 15) * 4;
        float4 f = *(const float4*)(&QKVG[(size_t)(s0 + sr) * NPAD + 2592 + hh * 64 + c4]);
        tile[sr][c4] = f.x; tile[sr][c4 + 1] = f.y; tile[sr][c4 + 2] = f.z; tile[sr][c4 + 3] = f.w;
    }
    __syncthreads();
    #pragma unroll
    for (int i = 0; i < 4; i++) {
        int idx = i * 256 + t;
        int dr = idx >> 4, c4 = (idx & 15) * 4;
        int hb = c4 >> 5, f = (c4 >> 4) & 1, g = (c4 >> 2) & 3;
        int p = (hb * 4 + g) * 8 + f * 4;
        ushort4 o;
        o.x = f2bf(tile[c4][dr]); o.y = f2bf(tile[c4 + 1][dr]);
        o.z = f2bf(tile[c4 + 2][dr]); o.w = f2bf(tile[c4 + 3][dr]);
        *(ushort4*)(&Vt[((size_t)hh * 64 + dr) * SLEN + s0 + p]) = o;
    }
}

// ---------------- sigmoid(gate) ----------------
__global__ void gate_sig_k(const float* __restrict__ QKVG, float* __restrict__ gate) {
    int i = blockIdx.x * 256 + threadIdx.x;
    int s = i >> 5, h = i & 31;
    float x = QKVG[(size_t)s * NPAD + 2048 + h];
    gate[i] = 1.f / (1.f + __expf(-x));
}

// ---------------- causal GQA flash attention + gate ----------------
// R4: one q-tile per block (grid 1024, big-first order for LPT packing) -> 3 blocks/CU
// (LDS-capped at 48KB), 12 waves/CU. R2's 3-buffer counted-vmcnt pipeline.
// setprio kept here (attn blocks run at independent phases; m191 +4-7%).
__global__ __launch_bounds__(256) void attn_k(const unsigned short* __restrict__ Qr,
                                              const unsigned short* __restrict__ Kr,
                                              const unsigned short* __restrict__ Vt,
                                              const float* __restrict__ gate,
                                              unsigned short* __restrict__ attn) {
    __shared__ unsigned short Kls[3][64 * 64];
    __shared__ unsigned short Vls[3][64 * 64];
    int d = blockIdx.x;
    int kvh = d & 7;
    int h = kvh * 4 + ((d >> 3) & 3);
    int qt = 31 - (d >> 5);          // big-first: span-32 blocks dispatch first
    int t = threadIdx.x, w = t >> 6, l = t & 63;
    int ql = l & 15, g = l >> 4;
    const float NEGINF = -__builtin_inff();

    const unsigned short* Kh = Kr + (size_t)kvh * SLEN * 64;
    const unsigned short* Vh = Vt + (size_t)kvh * 64 * SLEN;
    const unsigned short* Qh = Qr + (size_t)h * SLEN * 64;
    int lk = g * 8;
    // staging lane geometry: 8 rows x 8 chunks of 16B per gl_lds16
    int r8 = l >> 3, c8 = l & 7;
    int cs = 8 * (c8 ^ r8);          // pre-swizzled source col (shorts)
    int R0 = w * 16, R1 = w * 16 + 8;
    int rdswz = (ql & 7) << 4;       // read-side XOR swizzle (bytes)

    int q0 = qt * 64;
    int qrow = q0 + w * 16 + ql;

    bh8 qa0 = *(const bh8*)(Qh + (size_t)qrow * 64 + lk);
    bh8 qa1 = *(const bh8*)(Qh + (size_t)qrow * 64 + 32 + lk);

    f32x4 o[4];
    #pragma unroll
    for (int i = 0; i < 4; i++) o[i] = {0.f, 0.f, 0.f, 0.f};
    float m2 = NEGINF, lsum = 0.f;

    int ntiles = qt + 1;
    // prologue: stage tile 0 -> buf0, tile 1 -> buf1 (4 loads/wave each)
    {
        gl_lds16(&Kh[(size_t)(0 + R0 + r8) * 64 + cs], &Kls[0][R0 * 64]);
        gl_lds16(&Kh[(size_t)(0 + R1 + r8) * 64 + cs], &Kls[0][R1 * 64]);
        gl_lds16(&Vh[(size_t)(R0 + r8) * SLEN + 0 + cs], &Vls[0][R0 * 64]);
        gl_lds16(&Vh[(size_t)(R1 + r8) * SLEN + 0 + cs], &Vls[0][R1 * 64]);
    }
    if (ntiles > 1) {
        gl_lds16(&Kh[(size_t)(64 + R0 + r8) * 64 + cs], &Kls[1][R0 * 64]);
        gl_lds16(&Kh[(size_t)(64 + R1 + r8) * 64 + cs], &Kls[1][R1 * 64]);
        gl_lds16(&Vh[(size_t)(R0 + r8) * SLEN + 64 + cs], &Vls[1][R0 * 64]);
        gl_lds16(&Vh[(size_t)(R1 + r8) * SLEN + 64 + cs], &Vls[1][R1 * 64]);
    }
    int rd = 0, wr = 2;

    for (int ti = 0; ti < ntiles; ti++) {
        // wait my tile-ti loads (keep tile-ti+1 in flight), then sync all waves.
        if (ti + 1 < ntiles) asm volatile("s_waitcnt vmcnt(4)\n\ts_barrier" ::: "memory");
        else                 asm volatile("s_waitcnt vmcnt(0)\n\ts_barrier" ::: "memory");
        // stage tile ti+2 into buf[wr] (last read at iter ti-1; barrier ordered it)
        if (ti + 2 < ntiles) {
            int kv1 = (ti + 2) * 64;
            gl_lds16(&Kh[(size_t)(kv1 + R0 + r8) * 64 + cs], &Kls[wr][R0 * 64]);
            gl_lds16(&Kh[(size_t)(kv1 + R1 + r8) * 64 + cs], &Kls[wr][R1 * 64]);
            gl_lds16(&Vh[(size_t)(R0 + r8) * SLEN + kv1 + cs], &Vls[wr][R0 * 64]);
            gl_lds16(&Vh[(size_t)(R1 + r8) * SLEN + kv1 + cs], &Vls[wr][R1 * 64]);
        }
        const unsigned short* Kb = &Kls[rd][0];
        const unsigned short* Vb = &Vls[rd][0];
        int kv0 = ti * 64;
        // ---- QK^T (swapped): sct[nt][j] = S^T[key=kv0+nt*16+4g+j][q=qrow] (log2 units)
        f32x4 sct[4];
        __builtin_amdgcn_s_setprio(1);
        #pragma unroll
        for (int nt = 0; nt < 4; nt++) {
            int rb = (nt * 16 + ql) * 128;
            bh8 kb0 = *(const bh8*)(&Kb[(rb + ((g * 16) ^ rdswz)) >> 1]);
            bh8 kb1 = *(const bh8*)(&Kb[(rb + ((64 + g * 16) ^ rdswz)) >> 1]);
            f32x4 a = {0.f, 0.f, 0.f, 0.f};
            a = __builtin_amdgcn_mfma_f32_16x16x32_bf16(kb0, qa0, a, 0, 0, 0);
            a = __builtin_amdgcn_mfma_f32_16x16x32_bf16(kb1, qa1, a, 0, 0, 0);
            sct[nt] = a;
        }
        __builtin_amdgcn_s_setprio(0);
        // ---- causal mask (diag tile only)
        if (ti == qt) {
            #pragma unroll
            for (int nt = 0; nt < 4; nt++)
                #pragma unroll
                for (int j = 0; j < 4; j++) {
                    int key = kv0 + nt * 16 + 4 * g + j;
                    if (key > qrow) sct[nt][j] = NEGINF;
                }
        }
        // ---- online softmax (log2 domain), per-q reduce = regs + 2 shfl
        float mt0 = fmaxf(fmaxf(sct[0][0], sct[0][1]), fmaxf(sct[0][2], sct[0][3]));
        float mt1 = fmaxf(fmaxf(sct[1][0], sct[1][1]), fmaxf(sct[1][2], sct[1][3]));
        float mt2 = fmaxf(fmaxf(sct[2][0], sct[2][1]), fmaxf(sct[2][2], sct[2][3]));
        float mt3 = fmaxf(fmaxf(sct[3][0], sct[3][1]), fmaxf(sct[3][2], sct[3][3]));
        float mt = fmaxf(fmaxf(mt0, mt1), fmaxf(mt2, mt3));
        mt = fmaxf(mt, __shfl_xor(mt, 16));
        mt = fmaxf(mt, __shfl_xor(mt, 32));
        // defer-max: only rescale when tile max beats running max by >8 (log2 units)
        if (!__all(mt - m2 <= 8.f)) {
            float mnew = fmaxf(m2, mt);
            float resc = __builtin_amdgcn_exp2f(m2 - mnew);
            m2 = mnew;
            lsum *= resc;
            float rf[4];
            #pragma unroll
            for (int j = 0; j < 4; j++) rf[j] = __shfl(resc, 4 * g + j);
            #pragma unroll
            for (int nt = 0; nt < 4; nt++) {
                f32x4 oo = o[nt];
                #pragma unroll
                for (int j = 0; j < 4; j++) oo[j] *= rf[j];
                o[nt] = oo;
            }
        }
        float ps = 0.f;
        #pragma unroll
        for (int nt = 0; nt < 4; nt++)
            #pragma unroll
            for (int j = 0; j < 4; j++) {
                float p = __builtin_amdgcn_exp2f(sct[nt][j] - m2);
                sct[nt][j] = p;
                ps += p;
            }
        ps += __shfl_xor(ps, 16);
        ps += __shfl_xor(ps, 32);
        lsum += ps;
        // ---- P -> bf16 A-fragments, lane-local (key-permutation pi), HW cvt_pk
        union { unsigned int u[4]; bh8 v; } pa0, pa1;
        pa0.u[0] = cvtpk_bf16(sct[0][0], sct[0][1]);
        pa0.u[1] = cvtpk_bf16(sct[0][2], sct[0][3]);
        pa0.u[2] = cvtpk_bf16(sct[1][0], sct[1][1]);
        pa0.u[3] = cvtpk_bf16(sct[1][2], sct[1][3]);
        pa1.u[0] = cvtpk_bf16(sct[2][0], sct[2][1]);
        pa1.u[1] = cvtpk_bf16(sct[2][2], sct[2][3]);
        pa1.u[2] = cvtpk_bf16(sct[3][0], sct[3][1]);
        pa1.u[3] = cvtpk_bf16(sct[3][2], sct[3][3]);
        // ---- PV: B-fragments are single b128 reads (Vt key order pre-permuted)
        __builtin_amdgcn_s_setprio(1);
        #pragma unroll
        for (int nt = 0; nt < 4; nt++) {
            int rb = (nt * 16 + ql) * 128;
            bh8 vb0 = *(const bh8*)(&Vb[(rb + ((g * 16) ^ rdswz)) >> 1]);
            bh8 vb1 = *(const bh8*)(&Vb[(rb + ((64 + g * 16) ^ rdswz)) >> 1]);
            o[nt] = __builtin_amdgcn_mfma_f32_16x16x32_bf16(pa0.v, vb0, o[nt], 0, 0, 0);
            o[nt] = __builtin_amdgcn_mfma_f32_16x16x32_bf16(pa1.v, vb1, o[nt], 0, 0, 0);
        }
        __builtin_amdgcn_s_setprio(0);
        rd = (rd == 2) ? 0 : rd + 1;
        wr = (wr == 2) ? 0 : wr + 1;
    }

    // ---- epilogue: normalize, gate, store (o row q = 4g+j, col d = nt*16+ql)
    float gf[4];
    #pragma unroll
    for (int j = 0; j < 4; j++) {
        float ls = __shfl(lsum, 4 * g + j);
        int row = q0 + w * 16 + 4 * g + j;
        gf[j] = gate[row * 32 + h] / ls;
    }
    #pragma unroll
    for (int j = 0; j < 4; j++) {
        int row = q0 + w * 16 + 4 * g + j;
        #pragma unroll
        for (int nt = 0; nt < 4; nt++)
            attn[(size_t)row * 2048 + h * 64 + nt * 16 + ql] = f2bf(o[nt][j] * gf[j]);
    }
}

extern "C" void kernel_launch(void* const* d_in, const int* in_sizes, int n_in,
                              void* d_out, int out_size, void* d_ws, size_t ws_size,
                              hipStream_t stream) {
    const float* hidden = (const float*)d_in[0];
    const float* Wq = (const float*)d_in[1];
    const float* Wk = (const float*)d_in[2];
    const float* Wv = (const float*)d_in[3];
    const float* Wo = (const float*)d_in[4];
    const float* gq = (const float*)d_in[5];
    const float* gk = (const float*)d_in[6];
    float* out = (float*)d_out;
    char* ws = (char*)d_ws;

    unsigned short* X    = (unsigned short*)(ws + 0);         //  8388608 B
    unsigned short* Wt   = (unsigned short*)(ws + 8388608);   // 13107200 B
    float*          QKVG = (float*)(ws + 21495808);           // 26214400 B
    unsigned short* Qr   = (unsigned short*)(ws + 47710208);  //  8388608 B
    unsigned short* Kr   = (unsigned short*)(ws + 56098816);  //  2097152 B
    unsigned short* Vt   = (unsigned short*)(ws + 58195968);  //  2097152 B
    float*          gate = (float*)(ws + 60293120);           //   262144 B
    unsigned short* attn = (unsigned short*)(ws + 60555264);  //  8388608 B
    unsigned short* Wot  = (unsigned short*)(ws + 68943872);  //  8388608 B

    cast_x_k<<<dim3(4096), dim3(256), 0, stream>>>(hidden, X, SLEN * HDIM);
    pack_wt_k<<<dim3(100, 64), dim3(256), 0, stream>>>(Wq, Wk, Wv, Wt);
    pack_wot_k<<<dim3(64, 64), dim3(256), 0, stream>>>(Wo, Wot);
    gemm_nt64_k<<<dim3(800), dim3(256), 0, stream>>>(X, Wt, QKVG, NPAD, 32);
    norm_rope_k<<<dim3(20480), dim3(256), 0, stream>>>(QKVG, Qr, Kr, gq, gk);
    vt_k<<<dim3(32, 8), dim3(256), 0, stream>>>(QKVG, Vt);
    gate_sig_k<<<dim3(256), dim3(256), 0, stream>>>(QKVG, gate);
    attn_k<<<dim3(1024), dim3(256), 0, stream>>>(Qr, Kr, Vt, gate, attn);
    gemm_nt64_k<<<dim3(512), dim3(256), 0, stream>>>(attn, Wot, out, 2048, 32);
}